// Round 6
// baseline (274.860 us; speedup 1.0000x reference)
//
#include <hip/hip_runtime.h>

#define B_ 4
#define S_ 2048
#define C_ 512
#define H_ 8
#define D_ 64
#define M_ 8192   // B_*S_

typedef short s8v __attribute__((ext_vector_type(8)));   // 8 bf16 (4 VGPRs)
typedef short s4v __attribute__((ext_vector_type(4)));   // 4 bf16 (2 VGPRs)
typedef float f4v __attribute__((ext_vector_type(4)));   // MFMA C/D
typedef unsigned short u16;
typedef unsigned int u32;

__device__ __forceinline__ u16 f2b(float f) {
    u32 u = __builtin_bit_cast(u32, f);
    u = u + 0x7fffu + ((u >> 16) & 1u);
    return (u16)(u >> 16);
}

// async 16B global->LDS; lds dest is wave-uniform base, lane i lands at +16*i
__device__ __forceinline__ void gl2lds16(const void* g, void* l) {
    __builtin_amdgcn_global_load_lds(
        (const __attribute__((address_space(1))) void*)g,
        (__attribute__((address_space(3))) void*)l, 16, 0, 0);
}

// ---------------------------------------------------------------------------
__global__ __launch_bounds__(256) void conv_k(const float* __restrict__ s,
                                              u16* __restrict__ d) {
    const int i = (blockIdx.x * 256 + threadIdx.x) * 4;
    const float4 v = *(const float4*)&s[i];
    ushort4 o;
    o.x = f2b(v.x); o.y = f2b(v.y); o.z = f2b(v.z); o.w = f2b(v.w);
    *(ushort4*)&d[i] = o;
}

// ---------------------------------------------------------------------------
// All six weight transposes in ONE launch: blockIdx.z selects the matrix.
// ---------------------------------------------------------------------------
__global__ __launch_bounds__(256) void trconv6_k(const float* __restrict__ s0,
                                                 const float* __restrict__ s1,
                                                 const float* __restrict__ s2,
                                                 const float* __restrict__ s3,
                                                 const float* __restrict__ s4,
                                                 const float* __restrict__ s5,
                                                 u16* __restrict__ d0,
                                                 u16* __restrict__ d1,
                                                 u16* __restrict__ d2,
                                                 u16* __restrict__ d3,
                                                 u16* __restrict__ d4,
                                                 u16* __restrict__ d5)
{
    const float* W; u16* Wt;
    switch (blockIdx.z) {
        case 0: W = s0; Wt = d0; break;
        case 1: W = s1; Wt = d1; break;
        case 2: W = s2; Wt = d2; break;
        case 3: W = s3; Wt = d3; break;
        case 4: W = s4; Wt = d4; break;
        default: W = s5; Wt = d5; break;
    }
    __shared__ float t[32][33];
    const int tx = threadIdx.x & 31, ty = threadIdx.x >> 5;
    const int n0 = blockIdx.x * 32, k0 = blockIdx.y * 32;
    #pragma unroll
    for (int i = 0; i < 4; ++i)
        t[ty + i * 8][tx] = W[(size_t)(k0 + ty + i * 8) * C_ + n0 + tx];
    __syncthreads();
    #pragma unroll
    for (int i = 0; i < 4; ++i)
        Wt[(size_t)(n0 + ty + i * 8) * C_ + k0 + tx] = f2b(t[tx][ty + i * 8]);
}

// ---------------------------------------------------------------------------
// bf16 MFMA GEMM, 64x128 tile (512 blocks -> 2/CU), BK=32, double-buffered.
// ---------------------------------------------------------------------------
template <bool OB>
__global__ __launch_bounds__(256) void gemm_k(const u16* __restrict__ A,
                                              const u16* __restrict__ Bt,
                                              const float* __restrict__ bias,
                                              void* __restrict__ outv)
{
    __shared__ u16 As[2][4][16][32];   // 4KB/buf
    __shared__ u16 Bs[2][8][16][32];   // 8KB/buf
    const int tid = threadIdx.x;
    const int lane = tid & 63, w = tid >> 6;
    const int q4 = lane >> 4, l16 = lane & 15;
    const int bm = blockIdx.y * 64, bn = blockIdx.x * 128;
    const int lr = lane >> 2, lc = (lane & 3) * 8;

    f4v acc[4][2];
    #pragma unroll
    for (int i = 0; i < 4; ++i)
        #pragma unroll
        for (int j = 0; j < 2; ++j) acc[i][j] = (f4v){0.f, 0.f, 0.f, 0.f};

    // prologue: tile 0 -> buf0. A: seg w; B: segs 2w, 2w+1.
    gl2lds16(A + (size_t)(bm + w * 16 + lr) * C_ + lc, (char*)As + w * 1024);
    #pragma unroll
    for (int r = 0; r < 2; ++r) {
        const int seg = w * 2 + r;
        gl2lds16(Bt + (size_t)(bn + seg * 16 + lr) * C_ + lc, (char*)Bs + seg * 1024);
    }

    for (int kt = 0; kt < 16; ++kt) {
        __syncthreads();
        const int buf = kt & 1;
        if (kt < 15) {
            const int nb = buf ^ 1, k0 = (kt + 1) * 32;
            gl2lds16(A + (size_t)(bm + w * 16 + lr) * C_ + k0 + lc,
                     (char*)As + nb * 4096 + w * 1024);
            #pragma unroll
            for (int r = 0; r < 2; ++r) {
                const int seg = w * 2 + r;
                gl2lds16(Bt + (size_t)(bn + seg * 16 + lr) * C_ + k0 + lc,
                         (char*)Bs + nb * 8192 + seg * 1024);
            }
        }
        s8v a[4], bfr[2];
        #pragma unroll
        for (int i = 0; i < 4; ++i) a[i] = *(const s8v*)&As[buf][i][l16][q4 * 8];
        #pragma unroll
        for (int j = 0; j < 2; ++j) {
            const int row = w * 32 + j * 16 + l16;
            bfr[j] = *(const s8v*)&Bs[buf][row >> 4][row & 15][q4 * 8];
        }
        #pragma unroll
        for (int i = 0; i < 4; ++i)
            #pragma unroll
            for (int j = 0; j < 2; ++j)
                acc[i][j] = __builtin_amdgcn_mfma_f32_16x16x32_bf16(a[i], bfr[j], acc[i][j], 0, 0, 0);
    }

    #pragma unroll
    for (int j = 0; j < 2; ++j) {
        const int n = bn + w * 32 + j * 16 + l16;
        const float bj = bias ? bias[n] : 0.0f;
        #pragma unroll
        for (int i = 0; i < 4; ++i) {
            const int m = bm + i * 16 + q4 * 4;
            #pragma unroll
            for (int reg = 0; reg < 4; ++reg) {
                const float vv = acc[i][j][reg] + bj;
                if constexpr (OB) ((u16*)outv)[(size_t)(m + reg) * C_ + n] = f2b(vv);
                else              ((float*)outv)[(size_t)(m + reg) * C_ + n] = vv;
            }
        }
    }
}

// ---------------------------------------------------------------------------
// Fused QKV projection (128x128 tiles, grid (12,64)). V output is written
// TRANSPOSED + XOR-swizzled directly into Vt[b,h,d,s] (vtr_k eliminated):
// within each 32-key span, 4-key group g stored at g ^ (d&7).
// ---------------------------------------------------------------------------
__global__ __launch_bounds__(256) void qkv_k(const u16* __restrict__ A,
                                             const u16* __restrict__ Wq,
                                             const u16* __restrict__ Wk,
                                             const u16* __restrict__ Wv,
                                             u16* __restrict__ oq,
                                             u16* __restrict__ ok,
                                             u16* __restrict__ ovt)
{
    __shared__ u16 As[2][8][16][32];
    __shared__ u16 Bs[2][8][16][32];
    const int tid = threadIdx.x;
    const int lane = tid & 63, w = tid >> 6;
    const int q4 = lane >> 4, l16 = lane & 15;
    const int wr = w >> 1, wc = w & 1;
    const int nt = blockIdx.x, which = nt >> 2;
    const u16* Bt = which == 0 ? Wq : (which == 1 ? Wk : Wv);
    const int bm = blockIdx.y * 128, bn = (nt & 3) * 128;
    const int lr = lane >> 2, lc = (lane & 3) * 8;

    f4v acc[4][4];
    #pragma unroll
    for (int i = 0; i < 4; ++i)
        #pragma unroll
        for (int j = 0; j < 4; ++j) acc[i][j] = (f4v){0.f, 0.f, 0.f, 0.f};

    #pragma unroll
    for (int r = 0; r < 2; ++r) {
        const int seg = r * 4 + w;
        const int row = seg * 16 + lr;
        gl2lds16(A  + (size_t)(bm + row) * C_ + lc, (char*)As + seg * 1024);
        gl2lds16(Bt + (size_t)(bn + row) * C_ + lc, (char*)Bs + seg * 1024);
    }
    for (int kt = 0; kt < 16; ++kt) {
        __syncthreads();
        const int buf = kt & 1;
        if (kt < 15) {
            const int nb = buf ^ 1, k0 = (kt + 1) * 32;
            #pragma unroll
            for (int r = 0; r < 2; ++r) {
                const int seg = r * 4 + w;
                const int row = seg * 16 + lr;
                gl2lds16(A  + (size_t)(bm + row) * C_ + k0 + lc, (char*)As + nb * 8192 + seg * 1024);
                gl2lds16(Bt + (size_t)(bn + row) * C_ + k0 + lc, (char*)Bs + nb * 8192 + seg * 1024);
            }
        }
        s8v a[4], bf[4];
        #pragma unroll
        for (int i = 0; i < 4; ++i) {
            const int row = wr * 64 + i * 16 + l16;
            a[i] = *(const s8v*)&As[buf][row >> 4][row & 15][q4 * 8];
        }
        #pragma unroll
        for (int j = 0; j < 4; ++j) {
            const int row = wc * 64 + j * 16 + l16;
            bf[j] = *(const s8v*)&Bs[buf][row >> 4][row & 15][q4 * 8];
        }
        #pragma unroll
        for (int i = 0; i < 4; ++i)
            #pragma unroll
            for (int j = 0; j < 4; ++j)
                acc[i][j] = __builtin_amdgcn_mfma_f32_16x16x32_bf16(a[i], bf[j], acc[i][j], 0, 0, 0);
    }

    if (which != 2) {
        u16* outp = which == 0 ? oq : ok;
        #pragma unroll
        for (int j = 0; j < 4; ++j) {
            const int n = bn + wc * 64 + j * 16 + l16;
            #pragma unroll
            for (int i = 0; i < 4; ++i) {
                const int m = bm + wr * 64 + i * 16 + q4 * 4;
                #pragma unroll
                for (int reg = 0; reg < 4; ++reg)
                    outp[(size_t)(m + reg) * C_ + n] = f2b(acc[i][j][reg]);
            }
        }
    } else {
        // V: transposed + swizzled write. m -> s, n -> (h,d).
        const int bglob = bm >> 11;            // batch (S_=2048 | 128)
        const int sbase = bm & (S_ - 1);
        #pragma unroll
        for (int j = 0; j < 4; ++j) {
            const int n = bn + wc * 64 + j * 16 + l16;
            const int h = n >> 6, d = n & 63;
            u16* vrow = ovt + ((size_t)(bglob * H_ + h) * D_ + d) * S_;
            const int xw = d & 7;
            #pragma unroll
            for (int i = 0; i < 4; ++i) {
                const int s = sbase + wr * 64 + i * 16 + q4 * 4;
                const int pg = ((s & 31) >> 2) ^ xw;
                s4v pv;
                #pragma unroll
                for (int reg = 0; reg < 4; ++reg) pv[reg] = (short)f2b(acc[i][j][reg]);
                *(s4v*)&vrow[(s & ~31) + (pg << 2)] = pv;
            }
        }
    }
}

// ---------------------------------------------------------------------------
// LayerNorm (512), fp32 in (+opt residual), fp32/bf16 out. 4 rows/block.
// ---------------------------------------------------------------------------
template <bool OB>
__global__ __launch_bounds__(256) void ln_k(const float* __restrict__ in,
                                            const float* __restrict__ res,
                                            const float* __restrict__ w,
                                            const float* __restrict__ bb,
                                            void* __restrict__ outv)
{
    const int lane = threadIdx.x & 63;
    const int row  = blockIdx.x * 4 + (threadIdx.x >> 6);
    const float* p = in + (size_t)row * C_;
    float4 v0 = *(const float4*)&p[lane * 4];
    float4 v1 = *(const float4*)&p[256 + lane * 4];
    if (res) {
        const float* rp = res + (size_t)row * C_;
        const float4 r0 = *(const float4*)&rp[lane * 4];
        const float4 r1 = *(const float4*)&rp[256 + lane * 4];
        v0.x += r0.x; v0.y += r0.y; v0.z += r0.z; v0.w += r0.w;
        v1.x += r1.x; v1.y += r1.y; v1.z += r1.z; v1.w += r1.w;
    }
    float s  = v0.x + v0.y + v0.z + v0.w + v1.x + v1.y + v1.z + v1.w;
    float ss = v0.x*v0.x + v0.y*v0.y + v0.z*v0.z + v0.w*v0.w
             + v1.x*v1.x + v1.y*v1.y + v1.z*v1.z + v1.w*v1.w;
    #pragma unroll
    for (int off = 32; off >= 1; off >>= 1) {
        s  += __shfl_xor(s, off);
        ss += __shfl_xor(ss, off);
    }
    const float mean = s * (1.0f / C_);
    const float var  = ss * (1.0f / C_) - mean * mean;
    const float rstd = rsqrtf(var + 1e-5f);

    const float4 w0 = *(const float4*)&w[lane * 4];
    const float4 w1 = *(const float4*)&w[256 + lane * 4];
    const float4 b0 = *(const float4*)&bb[lane * 4];
    const float4 b1 = *(const float4*)&bb[256 + lane * 4];
    float4 o0, o1;
    o0.x = (v0.x - mean) * rstd * w0.x + b0.x;
    o0.y = (v0.y - mean) * rstd * w0.y + b0.y;
    o0.z = (v0.z - mean) * rstd * w0.z + b0.z;
    o0.w = (v0.w - mean) * rstd * w0.w + b0.w;
    o1.x = (v1.x - mean) * rstd * w1.x + b1.x;
    o1.y = (v1.y - mean) * rstd * w1.y + b1.y;
    o1.z = (v1.z - mean) * rstd * w1.z + b1.z;
    o1.w = (v1.w - mean) * rstd * w1.w + b1.w;
    if constexpr (OB) {
        u16* op = (u16*)outv + (size_t)row * C_;
        ushort4 u0, u1;
        u0.x = f2b(o0.x); u0.y = f2b(o0.y); u0.z = f2b(o0.z); u0.w = f2b(o0.w);
        u1.x = f2b(o1.x); u1.y = f2b(o1.y); u1.z = f2b(o1.z); u1.w = f2b(o1.w);
        *(ushort4*)&op[lane * 4]       = u0;
        *(ushort4*)&op[256 + lane * 4] = u1;
    } else {
        float* op = (float*)outv + (size_t)row * C_;
        *(float4*)&op[lane * 4]       = o0;
        *(float4*)&op[256 + lane * 4] = o1;
    }
}

// ---------------------------------------------------------------------------
// Fused double-LayerNorm: y1 = LN(in+res)*w1+b1 (fp32 -> out1),
// y2 = LN(y1)*w2+b2 (bf16 -> out2). One wave per row, 4 rows/block.
// ---------------------------------------------------------------------------
__global__ __launch_bounds__(256) void ln2x_k(const float* __restrict__ in,
                                              const float* __restrict__ res,
                                              const float* __restrict__ w1,
                                              const float* __restrict__ b1,
                                              const float* __restrict__ w2,
                                              const float* __restrict__ b2,
                                              float* __restrict__ out1,
                                              u16* __restrict__ out2)
{
    const int lane = threadIdx.x & 63;
    const int row  = blockIdx.x * 4 + (threadIdx.x >> 6);
    const float* p  = in  + (size_t)row * C_;
    const float* rp = res + (size_t)row * C_;
    float4 v0 = *(const float4*)&p[lane * 4];
    float4 v1 = *(const float4*)&p[256 + lane * 4];
    {
        const float4 r0 = *(const float4*)&rp[lane * 4];
        const float4 r1 = *(const float4*)&rp[256 + lane * 4];
        v0.x += r0.x; v0.y += r0.y; v0.z += r0.z; v0.w += r0.w;
        v1.x += r1.x; v1.y += r1.y; v1.z += r1.z; v1.w += r1.w;
    }
    float s  = v0.x + v0.y + v0.z + v0.w + v1.x + v1.y + v1.z + v1.w;
    float ss = v0.x*v0.x + v0.y*v0.y + v0.z*v0.z + v0.w*v0.w
             + v1.x*v1.x + v1.y*v1.y + v1.z*v1.z + v1.w*v1.w;
    #pragma unroll
    for (int off = 32; off >= 1; off >>= 1) {
        s  += __shfl_xor(s, off);
        ss += __shfl_xor(ss, off);
    }
    float mean = s * (1.0f / C_);
    float var  = ss * (1.0f / C_) - mean * mean;
    float rstd = rsqrtf(var + 1e-5f);

    const float4 wA0 = *(const float4*)&w1[lane * 4];
    const float4 wA1 = *(const float4*)&w1[256 + lane * 4];
    const float4 bA0 = *(const float4*)&b1[lane * 4];
    const float4 bA1 = *(const float4*)&b1[256 + lane * 4];
    float4 y0, y1v;
    y0.x  = (v0.x - mean) * rstd * wA0.x + bA0.x;
    y0.y  = (v0.y - mean) * rstd * wA0.y + bA0.y;
    y0.z  = (v0.z - mean) * rstd * wA0.z + bA0.z;
    y0.w  = (v0.w - mean) * rstd * wA0.w + bA0.w;
    y1v.x = (v1.x - mean) * rstd * wA1.x + bA1.x;
    y1v.y = (v1.y - mean) * rstd * wA1.y + bA1.y;
    y1v.z = (v1.z - mean) * rstd * wA1.z + bA1.z;
    y1v.w = (v1.w - mean) * rstd * wA1.w + bA1.w;
    float* op1 = out1 + (size_t)row * C_;
    *(float4*)&op1[lane * 4]       = y0;
    *(float4*)&op1[256 + lane * 4] = y1v;

    // second LN over y
    s  = y0.x + y0.y + y0.z + y0.w + y1v.x + y1v.y + y1v.z + y1v.w;
    ss = y0.x*y0.x + y0.y*y0.y + y0.z*y0.z + y0.w*y0.w
       + y1v.x*y1v.x + y1v.y*y1v.y + y1v.z*y1v.z + y1v.w*y1v.w;
    #pragma unroll
    for (int off = 32; off >= 1; off >>= 1) {
        s  += __shfl_xor(s, off);
        ss += __shfl_xor(ss, off);
    }
    mean = s * (1.0f / C_);
    var  = ss * (1.0f / C_) - mean * mean;
    rstd = rsqrtf(var + 1e-5f);

    const float4 wB0 = *(const float4*)&w2[lane * 4];
    const float4 wB1 = *(const float4*)&w2[256 + lane * 4];
    const float4 bB0 = *(const float4*)&b2[lane * 4];
    const float4 bB1 = *(const float4*)&b2[256 + lane * 4];
    ushort4 u0, u1;
    u0.x = f2b((y0.x - mean) * rstd * wB0.x + bB0.x);
    u0.y = f2b((y0.y - mean) * rstd * wB0.y + bB0.y);
    u0.z = f2b((y0.z - mean) * rstd * wB0.z + bB0.z);
    u0.w = f2b((y0.w - mean) * rstd * wB0.w + bB0.w);
    u1.x = f2b((y1v.x - mean) * rstd * wB1.x + bB1.x);
    u1.y = f2b((y1v.y - mean) * rstd * wB1.y + bB1.y);
    u1.z = f2b((y1v.z - mean) * rstd * wB1.z + bB1.z);
    u1.w = f2b((y1v.w - mean) * rstd * wB1.w + bB1.w);
    u16* op2 = out2 + (size_t)row * C_;
    *(ushort4*)&op2[lane * 4]       = u0;
    *(ushort4*)&op2[256 + lane * 4] = u1;
}

// ---------------------------------------------------------------------------
// Causal flash attention, register-resident P, 128-query blocks.
// grid (16, H, B), 256 thr; wave w owns queries w*32..w*32+31 (2 groups of 16).
// Transposed scores (A=K rows, B=Q rows) -> lane holds P in the A-operand
// layout of mfma_f32_16x16x16bf16_1k; PV straight from registers.
// Constant-max softmax (exact); diag masking peeled behind a uniform branch.
// K/V^T double-buffered via global_load_lds; 32 KB LDS.
// ---------------------------------------------------------------------------
__global__ __launch_bounds__(256) void attn_k(const u16* __restrict__ Q,
                                              const u16* __restrict__ K,
                                              const u16* __restrict__ Vt,
                                              u16* __restrict__ O)
{
    __shared__ u16 Ks[2][2][64][32];   // [buf][kh][key][k32]   8KB/buf
    __shared__ u16 Vs[2][2][64][32];   // [buf][keyhalf][d][key32] (swizzled)
    const int tid = threadIdx.x;
    const int lane = tid & 63, w = tid >> 6;
    const int q4 = lane >> 4, l16 = lane & 15;
    const int x = blockIdx.x, h = blockIdx.y, b = blockIdx.z;
    const int qb = (x & 1) ? 15 - (x >> 1) : (x >> 1);   // 128-query tile id
    const size_t base  = ((size_t)b * S_) * C_ + h * D_;
    const size_t basev = ((size_t)(b * H_ + h)) * D_ * S_;
    const int lr = lane >> 2, lc = (lane & 3) * 8;

    // Q fragments direct to registers: query = qb*128 + w*32 + g*16 + l16
    s8v qf[2][2];
    #pragma unroll
    for (int g = 0; g < 2; ++g)
        #pragma unroll
        for (int kh = 0; kh < 2; ++kh)
            qf[g][kh] = *(const s8v*)&Q[base + (size_t)(qb * 128 + w * 32 + g * 16 + l16) * C_
                                        + kh * 32 + q4 * 8];

    // prologue: K/V^T tile 0 -> buf0
    #pragma unroll
    for (int r = 0; r < 2; ++r) {
        const int seg = r * 4 + w;
        const int row = (seg & 3) * 16 + lr;
        const int kh = seg >> 2;
        gl2lds16(K  + base  + (size_t)row * C_ + kh * 32 + lc, (char*)Ks + seg * 1024);
        gl2lds16(Vt + basev + (size_t)row * S_ + kh * 32 + lc, (char*)Vs + seg * 1024);
    }

    f4v o[2][4];
    float lp[2][4];
    #pragma unroll
    for (int g = 0; g < 2; ++g)
        #pragma unroll
        for (int j = 0; j < 4; ++j) { o[g][j] = (f4v){0.f, 0.f, 0.f, 0.f}; lp[g][j] = 0.f; }

    const int nt = 2 * qb + 2;
    for (int kb = 0; kb < nt; ++kb) {
        __syncthreads();
        const int buf = kb & 1;
        if (kb + 1 < nt) {
            const int nb = buf ^ 1, kn = kb + 1;
            #pragma unroll
            for (int r = 0; r < 2; ++r) {
                const int seg = r * 4 + w;
                const int row = (seg & 3) * 16 + lr;
                const int kh = seg >> 2;
                gl2lds16(K  + base  + (size_t)(kn * 64 + row) * C_ + kh * 32 + lc,
                         (char*)Ks + nb * 8192 + seg * 1024);
                gl2lds16(Vt + basev + (size_t)row * S_ + kn * 64 + kh * 32 + lc,
                         (char*)Vs + nb * 8192 + seg * 1024);
            }
        }

        // transposed scores; K-frag shared across both query groups
        f4v sc[2][4];
        #pragma unroll
        for (int g = 0; g < 2; ++g)
            #pragma unroll
            for (int j = 0; j < 4; ++j) sc[g][j] = (f4v){0.f, 0.f, 0.f, 0.f};
        #pragma unroll
        for (int kh = 0; kh < 2; ++kh) {
            #pragma unroll
            for (int j = 0; j < 4; ++j) {
                const s8v kf = *(const s8v*)&Ks[buf][kh][j * 16 + l16][q4 * 8];
                #pragma unroll
                for (int g = 0; g < 2; ++g)
                    sc[g][j] = __builtin_amdgcn_mfma_f32_16x16x32_bf16(kf, qf[g][kh], sc[g][j], 0, 0, 0);
            }
        }

        // p = exp2(s*0.125*log2e - 8*log2e); bf16 by truncation
        s4v pa[2][4];
        if (kb >= 2 * qb) {   // diagonal-adjacent tiles: apply causal mask
            #pragma unroll
            for (int g = 0; g < 2; ++g) {
                const int qrow = qb * 128 + w * 32 + g * 16 + l16;
                #pragma unroll
                for (int j = 0; j < 4; ++j) {
                    float ps = 0.0f;
                    #pragma unroll
                    for (int reg = 0; reg < 4; ++reg) {
                        const int key = kb * 64 + j * 16 + q4 * 4 + reg;
                        float t = fmaf(sc[g][j][reg], 0.18033688011112043f, -11.541560327111707f);
                        if (key > qrow) t = -128.0f;
                        const float p = exp2f(t);
                        ps += p;
                        pa[g][j][reg] = (short)(__builtin_bit_cast(u32, p) >> 16);
                    }
                    lp[g][j] += ps;
                }
            }
        } else {              // interior tiles: no masking
            #pragma unroll
            for (int g = 0; g < 2; ++g)
                #pragma unroll
                for (int j = 0; j < 4; ++j) {
                    float ps = 0.0f;
                    #pragma unroll
                    for (int reg = 0; reg < 4; ++reg) {
                        const float p = exp2f(fmaf(sc[g][j][reg], 0.18033688011112043f,
                                                   -11.541560327111707f));
                        ps += p;
                        pa[g][j][reg] = (short)(__builtin_bit_cast(u32, p) >> 16);
                    }
                    lp[g][j] += ps;
                }
        }

        // PV from registers; V-frag shared across both query groups
        #pragma unroll
        for (int c = 0; c < 4; ++c) {
            const int gh = (((c & 1) * 4 + q4) ^ (l16 & 7)) * 4;
            #pragma unroll
            for (int dj = 0; dj < 4; ++dj) {
                const s4v vb = *(const s4v*)&Vs[buf][c >> 1][dj * 16 + l16][gh];
                #pragma unroll
                for (int g = 0; g < 2; ++g)
                    o[g][dj] = __builtin_amdgcn_mfma_f32_16x16x16bf16_1k(pa[g][c], vb, o[g][dj], 0, 0, 0);
            }
        }
    }

    // epilogue: reduce l across quads, per-row inv via shuffle
    #pragma unroll
    for (int g = 0; g < 2; ++g) {
        float lt = (lp[g][0] + lp[g][1]) + (lp[g][2] + lp[g][3]);
        lt += __shfl_xor(lt, 16);
        lt += __shfl_xor(lt, 32);
        #pragma unroll
        for (int reg = 0; reg < 4; ++reg) {
            const float inv = 1.0f / __shfl(lt, q4 * 4 + reg);
            const size_t rowoff = base + (size_t)(qb * 128 + w * 32 + g * 16 + q4 * 4 + reg) * C_;
            #pragma unroll
            for (int dj = 0; dj < 4; ++dj)
                O[rowoff + dj * 16 + l16] = f2b(o[g][dj][reg] * inv);
        }
    }
}

// ---------------------------------------------------------------------------
extern "C" void kernel_launch(void* const* d_in, const int* in_sizes, int n_in,
                              void* d_out, int out_size, void* d_ws, size_t ws_size,
                              hipStream_t stream)
{
    const float* x       = (const float*)d_in[0];
    const float* Wq      = (const float*)d_in[1];
    const float* Wk      = (const float*)d_in[2];
    const float* Wv      = (const float*)d_in[3];
    const float* Wo      = (const float*)d_in[4];
    const float* ln1_w   = (const float*)d_in[5];
    const float* ln1_b   = (const float*)d_in[6];
    const float* ffln1_w = (const float*)d_in[7];
    const float* ffln1_b = (const float*)d_in[8];
    const float* ff_w1   = (const float*)d_in[9];
    const float* ff_b1   = (const float*)d_in[10];
    const float* ffln2_w = (const float*)d_in[11];
    const float* ffln2_b = (const float*)d_in[12];
    const float* ff_w2   = (const float*)d_in[13];
    const float* ff_b2   = (const float*)d_in[14];
    const float* ln2_w   = (const float*)d_in[15];
    const float* ln2_b   = (const float*)d_in[16];
    float* out = (float*)d_out;

    const size_t MC = (size_t)M_ * C_;   // 4,194,304
    const size_t WW = (size_t)C_ * C_;
    u16* xb   = (u16*)d_ws;
    u16* WqT  = xb + MC;
    u16* WkT  = WqT + WW;
    u16* WvT  = WkT + WW;
    u16* WoT  = WvT + WW;
    u16* W1T  = WoT + WW;
    u16* W2T  = W1T + WW;
    u16* qbuf = W2T + WW;
    u16* kbuf = qbuf + MC;
    u16* vbuf = kbuf + MC;     // (unused spare)
    u16* vtbuf= vbuf + MC;
    u16* abuf = xb;               // xb dead after qkv_k; reused for attn out
    float* tf  = (float*)qbuf;    // overlays qbuf+kbuf (dead after attn)
    float* xln = (float*)vbuf;    // overlays vbuf+vtbuf (dead after attn)
    u16*   lnb = xb;              // same region, reused again after abuf dead

    const dim3 gg(C_ / 128, M_ / 64);    // (4, 128) = 512 blocks
    const dim3 gq(12, M_ / 128);         // fused QKV
    const dim3 ga(16, H_, B_);           // 512 attn blocks (128-query tiles)
    const dim3 gt(16, 16, 6);            // all 6 weight transposes
    const int  gl = M_ / 4;

    conv_k<<<MC / 1024, 256, 0, stream>>>(x, xb);
    trconv6_k<<<gt, 256, 0, stream>>>(Wq, Wk, Wv, Wo, ff_w1, ff_w2,
                                      WqT, WkT, WvT, WoT, W1T, W2T);

    qkv_k<<<gq, 256, 0, stream>>>(xb, WqT, WkT, WvT, qbuf, kbuf, vtbuf);
    attn_k<<<ga, 256, 0, stream>>>(qbuf, kbuf, vtbuf, abuf);
    gemm_k<false><<<gg, 256, 0, stream>>>(abuf, WoT, nullptr, tf);
    ln2x_k<<<gl, 256, 0, stream>>>(tf, x, ln1_w, ln1_b, ffln1_w, ffln1_b,
                                   xln, lnb);
    gemm_k<false><<<gg, 256, 0, stream>>>(lnb, W1T, ff_b1, tf);
    ln_k<true><<<gl, 256, 0, stream>>>(tf, nullptr, ffln2_w, ffln2_b, lnb);
    gemm_k<false><<<gg, 256, 0, stream>>>(lnb, W2T, ff_b2, tf);
    ln_k<false><<<gl, 256, 0, stream>>>(tf, xln, ln2_w, ln2_b, out);
}

// Round 7
// 274.258 us; speedup vs baseline: 1.0022x; 1.0022x over previous
//
#include <hip/hip_runtime.h>

#define B_ 4
#define S_ 2048
#define C_ 512
#define H_ 8
#define D_ 64
#define M_ 8192   // B_*S_

typedef short s8v __attribute__((ext_vector_type(8)));   // 8 bf16 (4 VGPRs)
typedef short s4v __attribute__((ext_vector_type(4)));   // 4 bf16 (2 VGPRs)
typedef float f4v __attribute__((ext_vector_type(4)));   // MFMA C/D
typedef unsigned short u16;
typedef unsigned int u32;

__device__ __forceinline__ u16 f2b(float f) {
    u32 u = __builtin_bit_cast(u32, f);
    u = u + 0x7fffu + ((u >> 16) & 1u);
    return (u16)(u >> 16);
}

// async 16B global->LDS; lds dest is wave-uniform base, lane i lands at +16*i
__device__ __forceinline__ void gl2lds16(const void* g, void* l) {
    __builtin_amdgcn_global_load_lds(
        (const __attribute__((address_space(1))) void*)g,
        (__attribute__((address_space(3))) void*)l, 16, 0, 0);
}

// ---------------------------------------------------------------------------
__global__ __launch_bounds__(256) void conv_k(const float* __restrict__ s,
                                              u16* __restrict__ d) {
    const int i = (blockIdx.x * 256 + threadIdx.x) * 4;
    const float4 v = *(const float4*)&s[i];
    ushort4 o;
    o.x = f2b(v.x); o.y = f2b(v.y); o.z = f2b(v.z); o.w = f2b(v.w);
    *(ushort4*)&d[i] = o;
}

// ---------------------------------------------------------------------------
// All six weight transposes in ONE launch: blockIdx.z selects the matrix.
// ---------------------------------------------------------------------------
__global__ __launch_bounds__(256) void trconv6_k(const float* __restrict__ s0,
                                                 const float* __restrict__ s1,
                                                 const float* __restrict__ s2,
                                                 const float* __restrict__ s3,
                                                 const float* __restrict__ s4,
                                                 const float* __restrict__ s5,
                                                 u16* __restrict__ d0,
                                                 u16* __restrict__ d1,
                                                 u16* __restrict__ d2,
                                                 u16* __restrict__ d3,
                                                 u16* __restrict__ d4,
                                                 u16* __restrict__ d5)
{
    const float* W; u16* Wt;
    switch (blockIdx.z) {
        case 0: W = s0; Wt = d0; break;
        case 1: W = s1; Wt = d1; break;
        case 2: W = s2; Wt = d2; break;
        case 3: W = s3; Wt = d3; break;
        case 4: W = s4; Wt = d4; break;
        default: W = s5; Wt = d5; break;
    }
    __shared__ float t[32][33];
    const int tx = threadIdx.x & 31, ty = threadIdx.x >> 5;
    const int n0 = blockIdx.x * 32, k0 = blockIdx.y * 32;
    #pragma unroll
    for (int i = 0; i < 4; ++i)
        t[ty + i * 8][tx] = W[(size_t)(k0 + ty + i * 8) * C_ + n0 + tx];
    __syncthreads();
    #pragma unroll
    for (int i = 0; i < 4; ++i)
        Wt[(size_t)(n0 + ty + i * 8) * C_ + k0 + tx] = f2b(t[tx][ty + i * 8]);
}

// ---------------------------------------------------------------------------
// Fused QKV projection (128x128 tiles, grid (12,64)). V output is written
// TRANSPOSED + XOR-swizzled directly into Vt[b,h,d,s]: within each 32-key
// span, 4-key group g stored at g ^ (d&7).
// ---------------------------------------------------------------------------
__global__ __launch_bounds__(256) void qkv_k(const u16* __restrict__ A,
                                             const u16* __restrict__ Wq,
                                             const u16* __restrict__ Wk,
                                             const u16* __restrict__ Wv,
                                             u16* __restrict__ oq,
                                             u16* __restrict__ ok,
                                             u16* __restrict__ ovt)
{
    __shared__ u16 As[2][8][16][32];
    __shared__ u16 Bs[2][8][16][32];
    const int tid = threadIdx.x;
    const int lane = tid & 63, w = tid >> 6;
    const int q4 = lane >> 4, l16 = lane & 15;
    const int wr = w >> 1, wc = w & 1;
    const int nt = blockIdx.x, which = nt >> 2;
    const u16* Bt = which == 0 ? Wq : (which == 1 ? Wk : Wv);
    const int bm = blockIdx.y * 128, bn = (nt & 3) * 128;
    const int lr = lane >> 2, lc = (lane & 3) * 8;

    f4v acc[4][4];
    #pragma unroll
    for (int i = 0; i < 4; ++i)
        #pragma unroll
        for (int j = 0; j < 4; ++j) acc[i][j] = (f4v){0.f, 0.f, 0.f, 0.f};

    #pragma unroll
    for (int r = 0; r < 2; ++r) {
        const int seg = r * 4 + w;
        const int row = seg * 16 + lr;
        gl2lds16(A  + (size_t)(bm + row) * C_ + lc, (char*)As + seg * 1024);
        gl2lds16(Bt + (size_t)(bn + row) * C_ + lc, (char*)Bs + seg * 1024);
    }
    for (int kt = 0; kt < 16; ++kt) {
        __syncthreads();
        const int buf = kt & 1;
        if (kt < 15) {
            const int nb = buf ^ 1, k0 = (kt + 1) * 32;
            #pragma unroll
            for (int r = 0; r < 2; ++r) {
                const int seg = r * 4 + w;
                const int row = seg * 16 + lr;
                gl2lds16(A  + (size_t)(bm + row) * C_ + k0 + lc, (char*)As + nb * 8192 + seg * 1024);
                gl2lds16(Bt + (size_t)(bn + row) * C_ + k0 + lc, (char*)Bs + nb * 8192 + seg * 1024);
            }
        }
        s8v a[4], bf[4];
        #pragma unroll
        for (int i = 0; i < 4; ++i) {
            const int row = wr * 64 + i * 16 + l16;
            a[i] = *(const s8v*)&As[buf][row >> 4][row & 15][q4 * 8];
        }
        #pragma unroll
        for (int j = 0; j < 4; ++j) {
            const int row = wc * 64 + j * 16 + l16;
            bf[j] = *(const s8v*)&Bs[buf][row >> 4][row & 15][q4 * 8];
        }
        #pragma unroll
        for (int i = 0; i < 4; ++i)
            #pragma unroll
            for (int j = 0; j < 4; ++j)
                acc[i][j] = __builtin_amdgcn_mfma_f32_16x16x32_bf16(a[i], bf[j], acc[i][j], 0, 0, 0);
    }

    if (which != 2) {
        u16* outp = which == 0 ? oq : ok;
        #pragma unroll
        for (int j = 0; j < 4; ++j) {
            const int n = bn + wc * 64 + j * 16 + l16;
            #pragma unroll
            for (int i = 0; i < 4; ++i) {
                const int m = bm + wr * 64 + i * 16 + q4 * 4;
                #pragma unroll
                for (int reg = 0; reg < 4; ++reg)
                    outp[(size_t)(m + reg) * C_ + n] = f2b(acc[i][j][reg]);
            }
        }
    } else {
        // V: transposed + swizzled write. m -> s, n -> (h,d).
        const int bglob = bm >> 11;
        const int sbase = bm & (S_ - 1);
        #pragma unroll
        for (int j = 0; j < 4; ++j) {
            const int n = bn + wc * 64 + j * 16 + l16;
            const int h = n >> 6, d = n & 63;
            u16* vrow = ovt + ((size_t)(bglob * H_ + h) * D_ + d) * S_;
            const int xw = d & 7;
            #pragma unroll
            for (int i = 0; i < 4; ++i) {
                const int s = sbase + wr * 64 + i * 16 + q4 * 4;
                const int pg = ((s & 31) >> 2) ^ xw;
                s4v pv;
                #pragma unroll
                for (int reg = 0; reg < 4; ++reg) pv[reg] = (short)f2b(acc[i][j][reg]);
                *(s4v*)&vrow[(s & ~31) + (pg << 2)] = pv;
            }
        }
    }
}

// ---------------------------------------------------------------------------
// Fused GEMM (32x512 row-complete tile) + LayerNorm epilogue.
// grid = M/32 = 256 blocks, 256 threads (4 waves, each owning n-slice 128).
// h = A@Bt (+bias) (+res);  y = LN(h)*wA+bA.
// TWO_LN: out1 = y (fp32), out2 = bf16(LN(y)*wB+bB).
// else:   out1 if !OB (fp32) / out2 if OB (bf16) gets y.
// ---------------------------------------------------------------------------
template <bool HAS_BIAS, bool HAS_RES, bool TWO_LN, bool OB>
__global__ __launch_bounds__(256) void fused_k(const u16* __restrict__ A,
                                               const u16* __restrict__ Bt,
                                               const float* __restrict__ bias,
                                               const float* __restrict__ res,
                                               const float* __restrict__ wA,
                                               const float* __restrict__ bA,
                                               const float* __restrict__ wB,
                                               const float* __restrict__ bB,
                                               float* __restrict__ out1,
                                               u16* __restrict__ out2)
{
    __shared__ u16 As_[2][2][16][32];    // [buf][seg][row16][k32]  2KB/buf
    __shared__ u16 Bs_[2][32][16][32];   // [buf][seg][row16][k32] 32KB/buf
    __shared__ float2 red[4][32];        // per-wave row partials (s, ss)
    const int tid = threadIdx.x;
    const int lane = tid & 63, w = tid >> 6;
    const int q4 = lane >> 4, l16 = lane & 15;
    const int bm = blockIdx.x * 32;
    const int lr = lane >> 2, lc = (lane & 3) * 8;

    f4v acc[2][8];
    #pragma unroll
    for (int i = 0; i < 2; ++i)
        #pragma unroll
        for (int j = 0; j < 8; ++j) acc[i][j] = (f4v){0.f, 0.f, 0.f, 0.f};

    // prologue: tile 0 -> buf0. A: 2 segs (waves 0-1); B: 32 segs (8/wave).
    if (w < 2)
        gl2lds16(A + (size_t)(bm + w * 16 + lr) * C_ + lc, (char*)As_ + w * 1024);
    #pragma unroll
    for (int r = 0; r < 8; ++r) {
        const int seg = w * 8 + r;
        gl2lds16(Bt + (size_t)(seg * 16 + lr) * C_ + lc, (char*)Bs_ + seg * 1024);
    }

    for (int kt = 0; kt < 16; ++kt) {
        __syncthreads();
        const int buf = kt & 1;
        if (kt < 15) {
            const int nb = buf ^ 1, k0 = (kt + 1) * 32;
            if (w < 2)
                gl2lds16(A + (size_t)(bm + w * 16 + lr) * C_ + k0 + lc,
                         (char*)As_ + nb * 2048 + w * 1024);
            #pragma unroll
            for (int r = 0; r < 8; ++r) {
                const int seg = w * 8 + r;
                gl2lds16(Bt + (size_t)(seg * 16 + lr) * C_ + k0 + lc,
                         (char*)Bs_ + nb * 32768 + seg * 1024);
            }
        }
        s8v a[2], bf[8];
        #pragma unroll
        for (int i = 0; i < 2; ++i) a[i] = *(const s8v*)&As_[buf][i][l16][q4 * 8];
        #pragma unroll
        for (int j = 0; j < 8; ++j) bf[j] = *(const s8v*)&Bs_[buf][w * 8 + j][l16][q4 * 8];
        #pragma unroll
        for (int i = 0; i < 2; ++i)
            #pragma unroll
            for (int j = 0; j < 8; ++j)
                acc[i][j] = __builtin_amdgcn_mfma_f32_16x16x32_bf16(a[i], bf[j], acc[i][j], 0, 0, 0);
    }

    // ------ epilogue: bias + residual, then LN over the full row ------
    if constexpr (HAS_BIAS) {
        #pragma unroll
        for (int j = 0; j < 8; ++j) {
            const float bj = bias[w * 128 + j * 16 + l16];
            #pragma unroll
            for (int i = 0; i < 2; ++i)
                #pragma unroll
                for (int reg = 0; reg < 4; ++reg) acc[i][j][reg] += bj;
        }
    }
    if constexpr (HAS_RES) {
        #pragma unroll
        for (int i = 0; i < 2; ++i)
            #pragma unroll
            for (int reg = 0; reg < 4; ++reg) {
                const float* rp = res + (size_t)(bm + i * 16 + q4 * 4 + reg) * C_;
                #pragma unroll
                for (int j = 0; j < 8; ++j)
                    acc[i][j][reg] += rp[w * 128 + j * 16 + l16];
            }
    }

    // stats pass 1
    float mean1[2][4], rstd1[2][4];
    {
        #pragma unroll
        for (int i = 0; i < 2; ++i)
            #pragma unroll
            for (int reg = 0; reg < 4; ++reg) {
                float s = 0.f, ss = 0.f;
                #pragma unroll
                for (int j = 0; j < 8; ++j) {
                    const float v = acc[i][j][reg];
                    s += v; ss += v * v;
                }
                #pragma unroll
                for (int off = 1; off <= 8; off <<= 1) {
                    s  += __shfl_xor(s, off);
                    ss += __shfl_xor(ss, off);
                }
                if (l16 == 0) red[w][i * 16 + q4 * 4 + reg] = make_float2(s, ss);
            }
        __syncthreads();
        #pragma unroll
        for (int i = 0; i < 2; ++i)
            #pragma unroll
            for (int reg = 0; reg < 4; ++reg) {
                const int r = i * 16 + q4 * 4 + reg;
                float S = 0.f, SS = 0.f;
                #pragma unroll
                for (int ww = 0; ww < 4; ++ww) {
                    const float2 f2 = red[ww][r];
                    S += f2.x; SS += f2.y;
                }
                const float mn = S * (1.0f / C_);
                mean1[i][reg] = mn;
                rstd1[i][reg] = rsqrtf(SS * (1.0f / C_) - mn * mn + 1e-5f);
            }
    }

    // y = (h - mean)*rstd*wA + bA  (in place)
    #pragma unroll
    for (int j = 0; j < 8; ++j) {
        const int n = w * 128 + j * 16 + l16;
        const float wj = wA[n], bj = bA[n];
        #pragma unroll
        for (int i = 0; i < 2; ++i)
            #pragma unroll
            for (int reg = 0; reg < 4; ++reg)
                acc[i][j][reg] = (acc[i][j][reg] - mean1[i][reg]) * rstd1[i][reg] * wj + bj;
    }

    if constexpr (TWO_LN) {
        // write y (fp32) to out1
        #pragma unroll
        for (int i = 0; i < 2; ++i)
            #pragma unroll
            for (int reg = 0; reg < 4; ++reg) {
                float* op = out1 + (size_t)(bm + i * 16 + q4 * 4 + reg) * C_;
                #pragma unroll
                for (int j = 0; j < 8; ++j)
                    op[w * 128 + j * 16 + l16] = acc[i][j][reg];
            }
        // stats pass 2 on y
        float mean2[2][4], rstd2[2][4];
        __syncthreads();   // red re-use hazard
        #pragma unroll
        for (int i = 0; i < 2; ++i)
            #pragma unroll
            for (int reg = 0; reg < 4; ++reg) {
                float s = 0.f, ss = 0.f;
                #pragma unroll
                for (int j = 0; j < 8; ++j) {
                    const float v = acc[i][j][reg];
                    s += v; ss += v * v;
                }
                #pragma unroll
                for (int off = 1; off <= 8; off <<= 1) {
                    s  += __shfl_xor(s, off);
                    ss += __shfl_xor(ss, off);
                }
                if (l16 == 0) red[w][i * 16 + q4 * 4 + reg] = make_float2(s, ss);
            }
        __syncthreads();
        #pragma unroll
        for (int i = 0; i < 2; ++i)
            #pragma unroll
            for (int reg = 0; reg < 4; ++reg) {
                const int r = i * 16 + q4 * 4 + reg;
                float S = 0.f, SS = 0.f;
                #pragma unroll
                for (int ww = 0; ww < 4; ++ww) {
                    const float2 f2 = red[ww][r];
                    S += f2.x; SS += f2.y;
                }
                const float mn = S * (1.0f / C_);
                mean2[i][reg] = mn;
                rstd2[i][reg] = rsqrtf(SS * (1.0f / C_) - mn * mn + 1e-5f);
            }
        #pragma unroll
        for (int j = 0; j < 8; ++j) {
            const int n = w * 128 + j * 16 + l16;
            const float wj = wB[n], bj = bB[n];
            #pragma unroll
            for (int i = 0; i < 2; ++i)
                #pragma unroll
                for (int reg = 0; reg < 4; ++reg) {
                    const float z = (acc[i][j][reg] - mean2[i][reg]) * rstd2[i][reg] * wj + bj;
                    out2[(size_t)(bm + i * 16 + q4 * 4 + reg) * C_ + n] = f2b(z);
                }
        }
    } else {
        #pragma unroll
        for (int i = 0; i < 2; ++i)
            #pragma unroll
            for (int reg = 0; reg < 4; ++reg) {
                const size_t ro = (size_t)(bm + i * 16 + q4 * 4 + reg) * C_;
                #pragma unroll
                for (int j = 0; j < 8; ++j) {
                    const int n = w * 128 + j * 16 + l16;
                    if constexpr (OB) out2[ro + n] = f2b(acc[i][j][reg]);
                    else              out1[ro + n] = acc[i][j][reg];
                }
            }
    }
}

// ---------------------------------------------------------------------------
// Causal flash attention, register-resident P (round-5 version). grid
// (32,H,B), 256 thr; wave w owns queries w*16..w*16+15 of a 64-query tile.
// Transposed scores -> lane holds P in mfma_16x16x16 A-operand layout; PV
// straight from registers. Constant-max softmax (exact). K/V^T double-
// buffered via global_load_lds; 32 KB LDS, VGPR ~48.
// ---------------------------------------------------------------------------
__global__ __launch_bounds__(256) void attn_k(const u16* __restrict__ Q,
                                              const u16* __restrict__ K,
                                              const u16* __restrict__ Vt,
                                              u16* __restrict__ O)
{
    __shared__ u16 Ks[2][2][64][32];   // [buf][kh][key][k32]   8KB/buf
    __shared__ u16 Vs[2][2][64][32];   // [buf][keyhalf][d][key32] (swizzled)
    const int tid = threadIdx.x;
    const int lane = tid & 63, w = tid >> 6;
    const int q4 = lane >> 4, l16 = lane & 15;
    const int x = blockIdx.x, h = blockIdx.y, b = blockIdx.z;
    const int qb = (x & 1) ? 31 - (x >> 1) : (x >> 1);
    const size_t base  = ((size_t)b * S_) * C_ + h * D_;
    const size_t basev = ((size_t)(b * H_ + h)) * D_ * S_;
    const int lr = lane >> 2, lc = (lane & 3) * 8;

    s8v qf[2];
    #pragma unroll
    for (int kh = 0; kh < 2; ++kh)
        qf[kh] = *(const s8v*)&Q[base + (size_t)(qb * 64 + w * 16 + l16) * C_ + kh * 32 + q4 * 8];

    #pragma unroll
    for (int r = 0; r < 2; ++r) {
        const int seg = r * 4 + w;
        const int row = (seg & 3) * 16 + lr;
        const int kh = seg >> 2;
        gl2lds16(K  + base  + (size_t)row * C_ + kh * 32 + lc, (char*)Ks + seg * 1024);
        gl2lds16(Vt + basev + (size_t)row * S_ + kh * 32 + lc, (char*)Vs + seg * 1024);
    }

    f4v o[4];
    float lp[4] = {0.f, 0.f, 0.f, 0.f};
    #pragma unroll
    for (int j = 0; j < 4; ++j) o[j] = (f4v){0.f, 0.f, 0.f, 0.f};

    const int qrow = w * 16 + l16;
    for (int kb = 0; kb <= qb; ++kb) {
        __syncthreads();
        const int buf = kb & 1;
        if (kb < qb) {
            const int nb = buf ^ 1, kn = kb + 1;
            #pragma unroll
            for (int r = 0; r < 2; ++r) {
                const int seg = r * 4 + w;
                const int row = (seg & 3) * 16 + lr;
                const int kh = seg >> 2;
                gl2lds16(K  + base  + (size_t)(kn * 64 + row) * C_ + kh * 32 + lc,
                         (char*)Ks + nb * 8192 + seg * 1024);
                gl2lds16(Vt + basev + (size_t)row * S_ + kn * 64 + kh * 32 + lc,
                         (char*)Vs + nb * 8192 + seg * 1024);
            }
        }

        f4v sc[4];
        #pragma unroll
        for (int j = 0; j < 4; ++j) sc[j] = (f4v){0.f, 0.f, 0.f, 0.f};
        #pragma unroll
        for (int kh = 0; kh < 2; ++kh) {
            #pragma unroll
            for (int j = 0; j < 4; ++j) {
                const s8v kf = *(const s8v*)&Ks[buf][kh][j * 16 + l16][q4 * 8];
                sc[j] = __builtin_amdgcn_mfma_f32_16x16x32_bf16(kf, qf[kh], sc[j], 0, 0, 0);
            }
        }

        const bool diag = (kb == qb);
        s4v pa[4];
        #pragma unroll
        for (int j = 0; j < 4; ++j) {
            float ps = 0.0f;
            #pragma unroll
            for (int reg = 0; reg < 4; ++reg) {
                float t = fmaf(sc[j][reg], 0.18033688011112043f, -11.541560327111707f);
                if (diag && (j * 16 + q4 * 4 + reg) > qrow) t = -128.0f;
                const float p = exp2f(t);
                ps += p;
                pa[j][reg] = (short)(__builtin_bit_cast(u32, p) >> 16);
            }
            lp[j] += ps;
        }

        #pragma unroll
        for (int c = 0; c < 4; ++c) {
            const int gh = (((c & 1) * 4 + q4) ^ (l16 & 7)) * 4;
            #pragma unroll
            for (int dj = 0; dj < 4; ++dj) {
                const s4v vb = *(const s4v*)&Vs[buf][c >> 1][dj * 16 + l16][gh];
                o[dj] = __builtin_amdgcn_mfma_f32_16x16x16bf16_1k(pa[c], vb, o[dj], 0, 0, 0);
            }
        }
    }

    float lt = (lp[0] + lp[1]) + (lp[2] + lp[3]);
    lt += __shfl_xor(lt, 16);
    lt += __shfl_xor(lt, 32);
    #pragma unroll
    for (int reg = 0; reg < 4; ++reg) {
        const float inv = 1.0f / __shfl(lt, q4 * 4 + reg);
        const size_t rowoff = base + (size_t)(qb * 64 + w * 16 + q4 * 4 + reg) * C_;
        #pragma unroll
        for (int dj = 0; dj < 4; ++dj)
            O[rowoff + dj * 16 + l16] = f2b(o[dj][reg] * inv);
    }
}

// ---------------------------------------------------------------------------
extern "C" void kernel_launch(void* const* d_in, const int* in_sizes, int n_in,
                              void* d_out, int out_size, void* d_ws, size_t ws_size,
                              hipStream_t stream)
{
    const float* x       = (const float*)d_in[0];
    const float* Wq      = (const float*)d_in[1];
    const float* Wk      = (const float*)d_in[2];
    const float* Wv      = (const float*)d_in[3];
    const float* Wo      = (const float*)d_in[4];
    const float* ln1_w   = (const float*)d_in[5];
    const float* ln1_b   = (const float*)d_in[6];
    const float* ffln1_w = (const float*)d_in[7];
    const float* ffln1_b = (const float*)d_in[8];
    const float* ff_w1   = (const float*)d_in[9];
    const float* ff_b1   = (const float*)d_in[10];
    const float* ffln2_w = (const float*)d_in[11];
    const float* ffln2_b = (const float*)d_in[12];
    const float* ff_w2   = (const float*)d_in[13];
    const float* ff_b2   = (const float*)d_in[14];
    const float* ln2_w   = (const float*)d_in[15];
    const float* ln2_b   = (const float*)d_in[16];
    float* out = (float*)d_out;

    const size_t MC = (size_t)M_ * C_;   // 4,194,304
    const size_t WW = (size_t)C_ * C_;
    u16* xb   = (u16*)d_ws;
    u16* WqT  = xb + MC;
    u16* WkT  = WqT + WW;
    u16* WvT  = WkT + WW;
    u16* WoT  = WvT + WW;
    u16* W1T  = WoT + WW;
    u16* W2T  = W1T + WW;
    u16* qbuf = W2T + WW;
    u16* kbuf = qbuf + MC;
    u16* vtbuf= kbuf + MC;
    // aliasing (row-matched, safe: each fused block reads only its own A rows
    // and writes only its own rows after the k-loop):
    u16*  abuf = xb;              // attn out; xb dead after qkv_k
    float* xln = (float*)qbuf;    // fp32 overlays qbuf+kbuf (dead after attn)

    const dim3 gq(12, M_ / 128);         // fused QKV
    const dim3 ga(32, H_, B_);           // 1024 attn blocks (64-query tiles)
    const dim3 gt(16, 16, 6);            // all 6 weight transposes
    const int  gf = M_ / 32;             // 256 fused-GEMM blocks

    conv_k<<<MC / 1024, 256, 0, stream>>>(x, xb);
    trconv6_k<<<gt, 256, 0, stream>>>(Wq, Wk, Wv, Wo, ff_w1, ff_w2,
                                      WqT, WkT, WvT, WoT, W1T, W2T);

    qkv_k<<<gq, 256, 0, stream>>>(xb, WqT, WkT, WvT, qbuf, kbuf, vtbuf);
    attn_k<<<ga, 256, 0, stream>>>(qbuf, kbuf, vtbuf, abuf);

    // t = a@Wo; xln = LN(t+x, ln1); lnb(bf16, ->xb) = LN(xln, ffln1)
    fused_k<false, true, true, true><<<gf, 256, 0, stream>>>(
        abuf, WoT, nullptr, x, ln1_w, ln1_b, ffln1_w, ffln1_b, xln, xb);
    // h1 = lnb@W1 + b1; out(bf16, ->xb) = LN(h1, ffln2)
    fused_k<true, false, false, true><<<gf, 256, 0, stream>>>(
        xb, W1T, ff_b1, nullptr, ffln2_w, ffln2_b, nullptr, nullptr, nullptr, xb);
    // h2 = h1ln@W2 + b2; out(fp32) = LN(h2 + xln, ln2)
    fused_k<true, true, false, false><<<gf, 256, 0, stream>>>(
        xb, W2T, ff_b2, xln, ln2_w, ln2_b, nullptr, nullptr, out, nullptr);
}